// Round 1
// baseline (261.946 us; speedup 1.0000x reference)
//
#include <hip/hip_runtime.h>

// Problem constants (from reference setup_inputs)
#define B_  32
#define L_  2048
#define D_  256
#define T_  64
#define KW  3
#define ROWS 32

// LDS layout for main kernel (floats)
#define XST   260          // x-tile row stride (floats), 65 float4
#define XST4  65
#define ATS   36           // attT row stride (floats), 9 float4
#define CST4  65           // C-tile float4 row stride
#define XS_FLOATS   (34 * XST)            // 8840
#define ATT_FLOATS  (T_ * ATS)            // 2304
#define CKS_FLOATS  24576                 // max(64*260=16640, 32*768=24576)
#define SMEM_FLOATS (XS_FLOATS + ATT_FLOATS + CKS_FLOATS)  // 35720 -> 142880 B

// ---------------------------------------------------------------------------
// Kernel 1: kc[t][j][d] = relu(b[j*D+d] + sum_dd C[t][dd] * W[dd][j*D+d])
// grid = (T_*KW), block = 256 (one output column d per thread)
// ---------------------------------------------------------------------------
__global__ __launch_bounds__(256) void kc_kernel(const float* __restrict__ C,
                                                 const float* __restrict__ W,
                                                 const float* __restrict__ bias,
                                                 float* __restrict__ kc) {
    __shared__ float Cs[D_];
    const int t   = blockIdx.x / KW;
    const int j   = blockIdx.x % KW;
    const int tid = threadIdx.x;

    Cs[tid] = C[t * D_ + tid];
    __syncthreads();

    const int m = j * D_ + tid;
    float acc = bias[m];
    #pragma unroll 8
    for (int dd = 0; dd < D_; ++dd)
        acc = fmaf(Cs[dd], W[dd * (KW * D_) + m], acc);
    kc[t * (KW * D_) + m] = fmaxf(acc, 0.0f);
}

// ---------------------------------------------------------------------------
// Kernel 2: fused main.
//   per block: b = blockIdx.y, rows l0..l0+31 (l0 = blockIdx.x*32)
//   phase 0: stage x rows l0-1..l0+32 and C into LDS
//   phase 1: attT[t][r] = sum_d x[l0+r][d] * C[t][d]
//   phase 2: for each t-half, stage kc half; thread d accumulates
//            oacc[r] += sum_j x[l0+r-1+j][d] * (sum_t att[r][t]*kc[t][j][d])
// ---------------------------------------------------------------------------
__global__ __launch_bounds__(256, 1) void main_kernel(const float* __restrict__ x,
                                                      const float* __restrict__ C,
                                                      const float* __restrict__ kc,
                                                      float* __restrict__ out) {
    __shared__ float smem[SMEM_FLOATS];
    float* xs   = smem;                       // [34][XST]
    float* attT = smem + XS_FLOATS;           // [64][ATS]
    float* cks  = smem + XS_FLOATS + ATT_FLOATS; // C-tile (phase1) / kc-half (phase2)

    const int tid = threadIdx.x;
    const int l0  = blockIdx.x * ROWS;
    const int b   = blockIdx.y;

    float4* xs4  = (float4*)xs;
    float4* cks4 = (float4*)cks;
    const float4* x4 = (const float4*)x;
    const float4* C4 = (const float4*)C;

    // ---- phase 0: stage x rows (l0-1 .. l0+32, zero-padded) and C ----
    for (int idx = tid; idx < 34 * 64; idx += 256) {
        const int row = idx >> 6;
        const int d4  = idx & 63;
        const int l   = l0 - 1 + row;
        float4 v = make_float4(0.f, 0.f, 0.f, 0.f);
        if (l >= 0 && l < L_)
            v = x4[((size_t)b * L_ + l) * 64 + d4];
        xs4[row * XST4 + d4] = v;
    }
    for (int idx = tid; idx < T_ * 64; idx += 256) {
        const int trow = idx >> 6;
        const int d4   = idx & 63;
        cks4[trow * CST4 + d4] = C4[idx];
    }
    __syncthreads();

    // ---- phase 1: att. Each thread: 2 rows x 4 t-values ----
    {
        const int tr = tid >> 4;       // 0..15 -> t0 = tr*4
        const int rr = tid & 15;       // 0..15 -> r0 = rr*2
        const int t0 = tr * 4;
        const int r0 = rr * 2;
        float acc[2][4];
        #pragma unroll
        for (int r = 0; r < 2; ++r)
            #pragma unroll
            for (int i = 0; i < 4; ++i) acc[r][i] = 0.f;

        const float4* xrow0 = xs4 + (r0 + 1) * XST4;   // att row r uses xs row r+1
        const float4* xrow1 = xs4 + (r0 + 2) * XST4;

        #pragma unroll 4
        for (int d4 = 0; d4 < 64; ++d4) {
            const float4 xv0 = xrow0[d4];
            const float4 xv1 = xrow1[d4];
            #pragma unroll
            for (int i = 0; i < 4; ++i) {
                const float4 cv = cks4[(t0 + i) * CST4 + d4];
                acc[0][i] = fmaf(xv0.x, cv.x, acc[0][i]);
                acc[0][i] = fmaf(xv0.y, cv.y, acc[0][i]);
                acc[0][i] = fmaf(xv0.z, cv.z, acc[0][i]);
                acc[0][i] = fmaf(xv0.w, cv.w, acc[0][i]);
                acc[1][i] = fmaf(xv1.x, cv.x, acc[1][i]);
                acc[1][i] = fmaf(xv1.y, cv.y, acc[1][i]);
                acc[1][i] = fmaf(xv1.z, cv.z, acc[1][i]);
                acc[1][i] = fmaf(xv1.w, cv.w, acc[1][i]);
            }
        }
        #pragma unroll
        for (int i = 0; i < 4; ++i) {
            attT[(t0 + i) * ATS + r0]     = acc[0][i];
            attT[(t0 + i) * ATS + r0 + 1] = acc[1][i];
        }
    }
    __syncthreads();   // attT ready; C-tile region free for kc halves

    // ---- phase 2 ----
    const int d = tid;
    float oacc[ROWS];
    #pragma unroll
    for (int r = 0; r < ROWS; ++r) oacc[r] = 0.f;

    const float4* attT4 = (const float4*)attT;

    for (int h = 0; h < 2; ++h) {
        // stage kc half: t = h*32 .. h*32+31  (layout matches global: [tt][j][d])
        const float4* kc4 = (const float4*)kc + h * 6144;
        for (int idx = tid; idx < 6144; idx += 256)
            cks4[idx] = kc4[idx];
        __syncthreads();

        #pragma unroll
        for (int rg = 0; rg < 2; ++rg) {
            float acc[16][3];
            #pragma unroll
            for (int i = 0; i < 16; ++i) {
                acc[i][0] = 0.f; acc[i][1] = 0.f; acc[i][2] = 0.f;
            }
            for (int tt = 0; tt < 32; ++tt) {
                const int t = h * 32 + tt;
                const float4 a0 = attT4[t * 9 + rg * 4 + 0];
                const float4 a1 = attT4[t * 9 + rg * 4 + 1];
                const float4 a2 = attT4[t * 9 + rg * 4 + 2];
                const float4 a3 = attT4[t * 9 + rg * 4 + 3];
                const float kc0 = cks[tt * 768 + d];
                const float kc1 = cks[tt * 768 + 256 + d];
                const float kc2 = cks[tt * 768 + 512 + d];
                const float av[16] = {a0.x, a0.y, a0.z, a0.w,
                                      a1.x, a1.y, a1.z, a1.w,
                                      a2.x, a2.y, a2.z, a2.w,
                                      a3.x, a3.y, a3.z, a3.w};
                #pragma unroll
                for (int i = 0; i < 16; ++i) {
                    acc[i][0] = fmaf(av[i], kc0, acc[i][0]);
                    acc[i][1] = fmaf(av[i], kc1, acc[i][1]);
                    acc[i][2] = fmaf(av[i], kc2, acc[i][2]);
                }
            }
            // fold 3-tap window into output accumulators (linear in t -> per-half ok)
            #pragma unroll
            for (int i = 0; i < 16; ++i) {
                const int r = rg * 16 + i;
                float o = oacc[r];
                o = fmaf(xs[(r + 0) * XST + d], acc[i][0], o);  // x[l0+r-1]
                o = fmaf(xs[(r + 1) * XST + d], acc[i][1], o);  // x[l0+r]
                o = fmaf(xs[(r + 2) * XST + d], acc[i][2], o);  // x[l0+r+1]
                oacc[r] = o;
            }
        }
        __syncthreads();   // all waves done reading this kc half
    }

    // ---- write out ----
    float* outp = out + ((size_t)b * L_ + l0) * D_ + d;
    #pragma unroll
    for (int r = 0; r < ROWS; ++r)
        outp[(size_t)r * D_] = oacc[r];
}

// ---------------------------------------------------------------------------
extern "C" void kernel_launch(void* const* d_in, const int* in_sizes, int n_in,
                              void* d_out, int out_size, void* d_ws, size_t ws_size,
                              hipStream_t stream) {
    const float* x    = (const float*)d_in[0];
    const float* C    = (const float*)d_in[1];
    const float* Wden = (const float*)d_in[2];
    const float* bden = (const float*)d_in[3];
    float* out = (float*)d_out;
    float* kc  = (float*)d_ws;   // T_*KW*D_ = 49152 floats = 192 KB

    kc_kernel<<<dim3(T_ * KW), dim3(256), 0, stream>>>(C, Wden, bden, kc);

    dim3 grid(L_ / ROWS, B_);
    main_kernel<<<grid, dim3(256), 0, stream>>>(x, C, kc, out);
}

// Round 2
// 156.470 us; speedup vs baseline: 1.6741x; 1.6741x over previous
//
#include <hip/hip_runtime.h>

// Problem constants (from reference setup_inputs)
#define B_  32
#define L_  2048
#define D_  256
#define T_  64
#define KW  3
#define ROWS 32

// LDS layout (floats). XST=260 pads x rows so phase-1 row-parallel reads are
// only 4-way bank conflicted (stride 256 would be 16-way).
#define XST   260
#define XST4  65
#define ATS   36            // attT row stride (9 float4)
#define XS_FLOATS   (34 * XST)            // 8840
#define ATT_FLOATS  (T_ * ATS)            // 2304
#define SMEM_FLOATS (XS_FLOATS + ATT_FLOATS)  // 11144 floats = 44576 B -> 3 blocks/CU

// ---------------------------------------------------------------------------
// Kernel 1: kc[t][j][d] = relu(b[j*D+d] + sum_dd C[t][dd] * W[dd][j*D+d])
// ---------------------------------------------------------------------------
__global__ __launch_bounds__(256) void kc_kernel(const float* __restrict__ C,
                                                 const float* __restrict__ W,
                                                 const float* __restrict__ bias,
                                                 float* __restrict__ kc) {
    __shared__ float Cs[D_];
    const int t   = blockIdx.x / KW;
    const int j   = blockIdx.x % KW;
    const int tid = threadIdx.x;

    Cs[tid] = C[t * D_ + tid];
    __syncthreads();

    const int m = j * D_ + tid;
    float acc = bias[m];
    #pragma unroll 8
    for (int dd = 0; dd < D_; ++dd)
        acc = fmaf(Cs[dd], W[dd * (KW * D_) + m], acc);
    kc[t * (KW * D_) + m] = fmaxf(acc, 0.0f);
}

// ---------------------------------------------------------------------------
// Kernel 2: fused main. C and kc are read straight from global (L2-resident,
// shared by all 2048 blocks); only the x-tile + attT live in LDS.
// ---------------------------------------------------------------------------
__global__ __launch_bounds__(256, 4) void main_kernel(const float* __restrict__ x,
                                                      const float* __restrict__ C,
                                                      const float* __restrict__ kc,
                                                      float* __restrict__ out) {
    __shared__ float smem[SMEM_FLOATS];
    float* xs   = smem;                 // [34][XST]
    float* attT = smem + XS_FLOATS;     // [64][ATS]

    const int tid = threadIdx.x;
    const int l0  = blockIdx.x * ROWS;
    const int b   = blockIdx.y;

    float4* xs4 = (float4*)xs;
    const float4* x4 = (const float4*)x;
    const float4* C4 = (const float4*)C;

    // ---- phase 0: stage x rows (l0-1 .. l0+32, zero-padded) ----
    for (int idx = tid; idx < 34 * 64; idx += 256) {
        const int row = idx >> 6;
        const int d4  = idx & 63;
        const int l   = l0 - 1 + row;
        float4 v = make_float4(0.f, 0.f, 0.f, 0.f);
        if (l >= 0 && l < L_)
            v = x4[((size_t)b * L_ + l) * 64 + d4];
        xs4[row * XST4 + d4] = v;
    }
    __syncthreads();

    // ---- phase 1: attT[t][r] = sum_d x[l0+r][d] * C[t][d] ----
    // Each thread: 2 rows x 4 t-values. C comes from global (L2-hot).
    {
        const int tr = tid >> 4;       // 0..15 -> t0 = tr*4
        const int rr = tid & 15;       // 0..15 -> r0 = rr*2
        const int t0 = tr * 4;
        const int r0 = rr * 2;
        float acc[2][4];
        #pragma unroll
        for (int r = 0; r < 2; ++r)
            #pragma unroll
            for (int i = 0; i < 4; ++i) acc[r][i] = 0.f;

        const float4* xrow0 = xs4 + (r0 + 1) * XST4;
        const float4* xrow1 = xs4 + (r0 + 2) * XST4;

        #pragma unroll 4
        for (int d4 = 0; d4 < 64; ++d4) {
            const float4 xv0 = xrow0[d4];
            const float4 xv1 = xrow1[d4];
            #pragma unroll
            for (int i = 0; i < 4; ++i) {
                const float4 cv = C4[(t0 + i) * 64 + d4];
                acc[0][i] = fmaf(xv0.x, cv.x, acc[0][i]);
                acc[0][i] = fmaf(xv0.y, cv.y, acc[0][i]);
                acc[0][i] = fmaf(xv0.z, cv.z, acc[0][i]);
                acc[0][i] = fmaf(xv0.w, cv.w, acc[0][i]);
                acc[1][i] = fmaf(xv1.x, cv.x, acc[1][i]);
                acc[1][i] = fmaf(xv1.y, cv.y, acc[1][i]);
                acc[1][i] = fmaf(xv1.z, cv.z, acc[1][i]);
                acc[1][i] = fmaf(xv1.w, cv.w, acc[1][i]);
            }
        }
        #pragma unroll
        for (int i = 0; i < 4; ++i) {
            attT[(t0 + i) * ATS + r0]     = acc[0][i];
            attT[(t0 + i) * ATS + r0 + 1] = acc[1][i];
        }
    }
    __syncthreads();

    // ---- phase 2: thread owns column d; kc from global (L2-hot) ----
    const int d = tid;
    const float4* attT4 = (const float4*)attT;

    #pragma unroll
    for (int rg = 0; rg < 2; ++rg) {
        float acc[16][3];
        #pragma unroll
        for (int i = 0; i < 16; ++i) {
            acc[i][0] = 0.f; acc[i][1] = 0.f; acc[i][2] = 0.f;
        }
        #pragma unroll 2
        for (int tt = 0; tt < T_; ++tt) {
            const float4 a0 = attT4[tt * 9 + rg * 4 + 0];
            const float4 a1 = attT4[tt * 9 + rg * 4 + 1];
            const float4 a2 = attT4[tt * 9 + rg * 4 + 2];
            const float4 a3 = attT4[tt * 9 + rg * 4 + 3];
            const float kc0 = kc[tt * 768 + d];
            const float kc1 = kc[tt * 768 + 256 + d];
            const float kc2 = kc[tt * 768 + 512 + d];
            const float av[16] = {a0.x, a0.y, a0.z, a0.w,
                                  a1.x, a1.y, a1.z, a1.w,
                                  a2.x, a2.y, a2.z, a2.w,
                                  a3.x, a3.y, a3.z, a3.w};
            #pragma unroll
            for (int i = 0; i < 16; ++i) {
                acc[i][0] = fmaf(av[i], kc0, acc[i][0]);
                acc[i][1] = fmaf(av[i], kc1, acc[i][1]);
                acc[i][2] = fmaf(av[i], kc2, acc[i][2]);
            }
        }
        // fold 3-tap window and store this 16-row group
        float* outp = out + ((size_t)b * L_ + l0 + rg * 16) * D_ + d;
        #pragma unroll
        for (int i = 0; i < 16; ++i) {
            const int r = rg * 16 + i;
            float o = 0.f;
            o = fmaf(xs[(r + 0) * XST + d], acc[i][0], o);  // x[l0+r-1]
            o = fmaf(xs[(r + 1) * XST + d], acc[i][1], o);  // x[l0+r]
            o = fmaf(xs[(r + 2) * XST + d], acc[i][2], o);  // x[l0+r+1]
            outp[(size_t)i * D_] = o;
        }
    }
}

// ---------------------------------------------------------------------------
extern "C" void kernel_launch(void* const* d_in, const int* in_sizes, int n_in,
                              void* d_out, int out_size, void* d_ws, size_t ws_size,
                              hipStream_t stream) {
    const float* x    = (const float*)d_in[0];
    const float* C    = (const float*)d_in[1];
    const float* Wden = (const float*)d_in[2];
    const float* bden = (const float*)d_in[3];
    float* out = (float*)d_out;
    float* kc  = (float*)d_ws;   // T_*KW*D_ = 49152 floats = 192 KB

    kc_kernel<<<dim3(T_ * KW), dim3(256), 0, stream>>>(C, Wden, bden, kc);

    dim3 grid(L_ / ROWS, B_);
    main_kernel<<<grid, dim3(256), 0, stream>>>(x, C, kc, out);
}

// Round 3
// 66.611 us; speedup vs baseline: 3.9325x; 2.3490x over previous
//
#include <hip/hip_runtime.h>

// Problem constants
#define B_  32
#define L_  2048
#define D_  256
#define T_  64
#define KW  3

typedef float f32x4 __attribute__((ext_vector_type(4)));
typedef short s16x8 __attribute__((ext_vector_type(8)));
typedef short s16x4 __attribute__((ext_vector_type(4)));

__device__ __forceinline__ short f2bf(float f) {
    unsigned u = __builtin_bit_cast(unsigned, f);
    u += 0x7FFFu + ((u >> 16) & 1u);          // round-to-nearest-even
    return (short)(u >> 16);
}
__device__ __forceinline__ float bf2f(short s) {
    unsigned u = ((unsigned)(unsigned short)s) << 16;
    return __builtin_bit_cast(float, u);
}

// ---------------------------------------------------------------------------
// prep A: Cbf[t][dd] = bf16(C[t][dd])   (16384 elems)
// ---------------------------------------------------------------------------
__global__ __launch_bounds__(256) void cbf_kernel(const float* __restrict__ C,
                                                  short* __restrict__ Cbf) {
    const int i = (blockIdx.x * 256 + threadIdx.x) * 4;
    f32x4 v = *(const f32x4*)(C + i);
    s16x4 s;
    s[0] = f2bf(v[0]); s[1] = f2bf(v[1]); s[2] = f2bf(v[2]); s[3] = f2bf(v[3]);
    *(s16x4*)(Cbf + i) = s;
}

// ---------------------------------------------------------------------------
// prep B: kcT[n][t] = bf16(relu(b[n] + sum_dd C[t][dd]*W[dd][n])), n in [0,768)
// grid 48 (16 n-rows each), block 256 = 64 t x 4 nl (each thread 4 n-values)
// ---------------------------------------------------------------------------
__global__ __launch_bounds__(256) void kc_prep(const float* __restrict__ C,
                                               const float* __restrict__ W,
                                               const float* __restrict__ bias,
                                               short* __restrict__ kcT) {
    __shared__ float Ws[256 * 16];
    const int tid = threadIdx.x;
    const int n0  = blockIdx.x * 16;

    for (int idx = tid; idx < 256 * 16; idx += 256) {
        const int dd = idx >> 4, nl = idx & 15;
        Ws[idx] = W[dd * (KW * D_) + n0 + nl];
    }
    __syncthreads();

    const int t  = tid >> 2;
    const int nl = tid & 3;
    float acc[4];
    #pragma unroll
    for (int i = 0; i < 4; ++i) acc[i] = bias[n0 + nl + 4 * i];

    const float* Crow = C + t * D_;
    for (int dd = 0; dd < D_; ++dd) {
        const float c = Crow[dd];
        #pragma unroll
        for (int i = 0; i < 4; ++i)
            acc[i] = fmaf(c, Ws[dd * 16 + nl + 4 * i], acc[i]);
    }
    #pragma unroll
    for (int i = 0; i < 4; ++i)
        kcT[(n0 + nl + 4 * i) * T_ + t] = f2bf(fmaxf(acc[i], 0.f));
}

// ---------------------------------------------------------------------------
// main: per block = (64 rows of one batch), 4 waves.
//  phase1: att[64][64] = x @ C^T via MFMA (A from LDS, B=Cbf from L2)
//  phase2: per wave: 4 d-tiles x 3 j x 4 M-tiles via MFMA (A=att LDS, B=kcT L2)
//          + 3-tap window fold in registers, fp32 store.
// ---------------------------------------------------------------------------
#define XST 264                 // xs row stride (shorts); 528B = 33*16 -> aligned
#define ATS 72                  // atts row stride (shorts); 144B = 9*16
#define XS_SH  (66 * XST)       // 17424 shorts
#define ATT_SH (64 * ATS)       // 4608 shorts  -> total 44064 B LDS

__global__ __launch_bounds__(256, 3) void main_kernel(const float* __restrict__ x,
                                                      const short* __restrict__ Cbf,
                                                      const short* __restrict__ kcT,
                                                      float* __restrict__ out) {
    __shared__ short sm[XS_SH + ATT_SH];
    short* xs   = sm;
    short* atts = sm + XS_SH;

    const int tid  = threadIdx.x;
    const int w    = tid >> 6;        // wave 0..3
    const int lane = tid & 63;
    const int c    = lane & 15;       // MFMA col / row-in-tile
    const int g    = lane >> 4;       // MFMA k-group / row-group
    const int l0   = blockIdx.x * 64;
    const int b    = blockIdx.y;

    // ---- stage x rows l0-1 .. l0+64 as bf16 ----
    const f32x4* x4 = (const f32x4*)(x + (size_t)b * L_ * D_);
    for (int idx = tid; idx < 66 * 64; idx += 256) {
        const int row = idx >> 6;
        const int d4  = idx & 63;
        const int l   = l0 - 1 + row;
        f32x4 v = {0.f, 0.f, 0.f, 0.f};
        if (l >= 0 && l < L_) v = x4[(size_t)l * 64 + d4];
        s16x4 s;
        s[0] = f2bf(v[0]); s[1] = f2bf(v[1]); s[2] = f2bf(v[2]); s[3] = f2bf(v[3]);
        *(s16x4*)&xs[row * XST + d4 * 4] = s;
    }
    __syncthreads();

    // ---- phase 1: wave w computes att rows [w*16, w*16+16) x all 64 t ----
    {
        f32x4 acc[4];
        #pragma unroll
        for (int tt = 0; tt < 4; ++tt) acc[tt] = (f32x4){0.f, 0.f, 0.f, 0.f};

        for (int ks = 0; ks < 8; ++ks) {
            const s16x8 a = *(const s16x8*)&xs[(1 + w * 16 + c) * XST + ks * 32 + g * 8];
            #pragma unroll
            for (int tt = 0; tt < 4; ++tt) {
                const s16x8 bf = *(const s16x8*)&Cbf[(tt * 16 + c) * D_ + ks * 32 + g * 8];
                acc[tt] = __builtin_amdgcn_mfma_f32_16x16x32_bf16(a, bf, acc[tt], 0, 0, 0);
            }
        }
        // D layout: col=lane&15 (t), row=(lane>>4)*4+reg (l) -> att[l][t] bf16 in LDS
        #pragma unroll
        for (int tt = 0; tt < 4; ++tt)
            #pragma unroll
            for (int r = 0; r < 4; ++r)
                atts[(w * 16 + g * 4 + r) * ATS + tt * 16 + c] = f2bf(acc[tt][r]);
    }
    __syncthreads();

    // ---- phase 2 ----
    // preload A-frags (att) for all 4 M-tiles, K=64 -> 2 ksteps
    s16x8 afr[4][2];
    #pragma unroll
    for (int m = 0; m < 4; ++m)
        #pragma unroll
        for (int ks = 0; ks < 2; ++ks)
            afr[m][ks] = *(const s16x8*)&atts[(m * 16 + c) * ATS + ks * 32 + g * 8];

    const size_t outBase = ((size_t)b * L_ + l0) * D_;

    #pragma unroll
    for (int dtl = 0; dtl < 4; ++dtl) {
        const int dcol = w * 64 + dtl * 16 + c;     // this lane's d column
        // B-frags: kcT rows n = j*256 + d-tile, 8 consecutive t contiguous
        s16x8 bfr[3][2];
        #pragma unroll
        for (int j = 0; j < 3; ++j)
            #pragma unroll
            for (int ks = 0; ks < 2; ++ks)
                bfr[j][ks] = *(const s16x8*)&kcT[(j * D_ + w * 64 + dtl * 16 + c) * T_ + ks * 32 + g * 8];

        #pragma unroll
        for (int m = 0; m < 4; ++m) {
            f32x4 a0 = (f32x4){0.f,0.f,0.f,0.f};
            f32x4 a1 = (f32x4){0.f,0.f,0.f,0.f};
            f32x4 a2 = (f32x4){0.f,0.f,0.f,0.f};
            a0 = __builtin_amdgcn_mfma_f32_16x16x32_bf16(afr[m][0], bfr[0][0], a0, 0, 0, 0);
            a0 = __builtin_amdgcn_mfma_f32_16x16x32_bf16(afr[m][1], bfr[0][1], a0, 0, 0, 0);
            a1 = __builtin_amdgcn_mfma_f32_16x16x32_bf16(afr[m][0], bfr[1][0], a1, 0, 0, 0);
            a1 = __builtin_amdgcn_mfma_f32_16x16x32_bf16(afr[m][1], bfr[1][1], a1, 0, 0, 0);
            a2 = __builtin_amdgcn_mfma_f32_16x16x32_bf16(afr[m][0], bfr[2][0], a2, 0, 0, 0);
            a2 = __builtin_amdgcn_mfma_f32_16x16x32_bf16(afr[m][1], bfr[2][1], a2, 0, 0, 0);

            // window fold: out[l,d] = sum_j ki_j[l,d] * x[l-1+j,d]
            // lane rows: l-l0 = m*16 + g*4 + r ; xs row (l-l0)+j
            float xv[6];
            #pragma unroll
            for (int i = 0; i < 6; ++i)
                xv[i] = bf2f(xs[(m * 16 + g * 4 + i) * XST + dcol]);

            #pragma unroll
            for (int r = 0; r < 4; ++r) {
                const float o = a0[r] * xv[r] + a1[r] * xv[r + 1] + a2[r] * xv[r + 2];
                out[outBase + (size_t)(m * 16 + g * 4 + r) * D_ + dcol] = o;
            }
        }
    }
}

// ---------------------------------------------------------------------------
extern "C" void kernel_launch(void* const* d_in, const int* in_sizes, int n_in,
                              void* d_out, int out_size, void* d_ws, size_t ws_size,
                              hipStream_t stream) {
    const float* x    = (const float*)d_in[0];
    const float* C    = (const float*)d_in[1];
    const float* Wden = (const float*)d_in[2];
    const float* bden = (const float*)d_in[3];
    float* out = (float*)d_out;

    short* kcT = (short*)d_ws;                  // [768][64] bf16 = 98304 B
    short* Cbf = (short*)d_ws + KW * D_ * T_;   // [64][256] bf16 = 32768 B

    cbf_kernel<<<dim3(16), dim3(256), 0, stream>>>(C, Cbf);
    kc_prep<<<dim3(48), dim3(256), 0, stream>>>(C, Wden, bden, kcT);

    dim3 grid(L_ / 64, B_);
    main_kernel<<<grid, dim3(256), 0, stream>>>(x, Cbf, kcT, out);
}